// Round 5
// baseline (1350.667 us; speedup 1.0000x reference)
//
#include <hip/hip_runtime.h>
#include <math.h>

// ---- model constants ----
#define BS_TOT   1024          // B*S
#define DM       256           // d_model
#define DST      128           // d_state
#define TSTEPS   8
#define DECAYF   0.6065306597126334f
#define SCALEF   0.17677669529663689f   // 1/sqrt(32)
#define NE       (BS_TOT * DM)          // 262144

// ======================= embedding =======================
__global__ void embed_k(const int* __restrict__ ids, const float* __restrict__ emb,
                        float* __restrict__ tok) {
    int r = blockIdx.x, c = threadIdx.x;
    tok[r * DM + c] = emb[(size_t)ids[r] * DM + c];
}

// ======================= per-layer state init =======================
__global__ void init_k(float* __restrict__ hb0, float* __restrict__ hb1,
                       float* __restrict__ svb0, float* __restrict__ svb1,
                       float* __restrict__ ovb0, float* __restrict__ ovb1,
                       int* __restrict__ cnts) {
    int i = blockIdx.x * 256 + threadIdx.x;
    if (i < BS_TOT * DST) { hb0[i] = 0.f; hb1[i] = 0.f; svb0[i] = 0.f; svb1[i] = 0.f; }
    ovb0[i] = 0.f; ovb1[i] = 0.f;        // grid is exactly 262144
    if (i < 16) cnts[i] = 0;             // cnt1[8], cnt2[8]
}

// ======================= k-half transpose: kv[key][0..127] -> kT[d][key] ============
__global__ __launch_bounds__(256) void ktrans_k(const float* __restrict__ kv,
                                                float* __restrict__ kT) {
    __shared__ float tile[64][133];
    const float* src = kv + (size_t)blockIdx.y * NE;
    float* dst = kT + (size_t)blockIdx.y * (128 * 1024);
    const int kc = blockIdx.x, tid = threadIdx.x;
#pragma unroll
    for (int i = 0; i < 32; ++i) {
        int idx = i * 256 + tid;
        int key = idx >> 7, d = idx & 127;
        tile[key][d] = src[(size_t)(kc * 64 + key) * 256 + d];
    }
    __syncthreads();
#pragma unroll
    for (int i = 0; i < 32; ++i) {
        int idx = i * 256 + tid;
        int d = idx >> 6, key = idx & 63;
        dst[(size_t)d * 1024 + kc * 64 + key] = tile[key][d];
    }
}

// ======================= time-mean =======================
__global__ void mean_k(const float* __restrict__ outs, float* __restrict__ ti) {
    int i = blockIdx.x * 256 + threadIdx.x;
    float s = 0.f;
#pragma unroll
    for (int t = 0; t < TSTEPS; ++t) s += outs[t * NE + i];
    ti[i] = s * 0.125f;
}

// ======================= generic fp32 GEMM (plain, +bias) =======================
template <int BM, int BN, int BK, int TM, int TN>
__global__ __launch_bounds__((BM / TM) * (BN / TN))
void gemm_k(const float* __restrict__ Amat, const float* __restrict__ Wmat,
            const float* __restrict__ bias, float* __restrict__ outp,
            int M, int N, int K) {
    constexpr int NT  = (BM / TM) * (BN / TN);
    constexpr int NXT = BN / TN;
    __shared__ float As[BK][BM + 4];
    __shared__ float Bs[BK][BN + 4];
    const int tid = threadIdx.x;
    const int n0 = blockIdx.x * BN, m0 = blockIdx.y * BM;
    const int tx = tid % NXT, ty = tid / NXT;
    float acc[TM][TN] = {};

    for (int k0 = 0; k0 < K; k0 += BK) {
#pragma unroll
        for (int i = 0; i < (BM * BK) / NT; ++i) {
            int idx = i * NT + tid;
            int kk = idx % BK, mm = idx / BK;
            As[kk][mm] = Amat[(size_t)(m0 + mm) * K + k0 + kk];
        }
#pragma unroll
        for (int i = 0; i < (BN * BK) / NT; ++i) {
            int idx = i * NT + tid;
            int kk = idx % BK, nn = idx / BK;
            Bs[kk][nn] = Wmat[(size_t)(n0 + nn) * K + k0 + kk];
        }
        __syncthreads();
#pragma unroll
        for (int kk = 0; kk < BK; ++kk) {
            float a[TM], b[TN];
#pragma unroll
            for (int i = 0; i < TM; ++i) a[i] = As[kk][ty * TM + i];
#pragma unroll
            for (int j = 0; j < TN; ++j) b[j] = Bs[kk][tx * TN + j];
#pragma unroll
            for (int i = 0; i < TM; ++i)
#pragma unroll
                for (int j = 0; j < TN; ++j) acc[i][j] += a[i] * b[j];
        }
        __syncthreads();
    }
#pragma unroll
    for (int i = 0; i < TM; ++i) {
        int mr = m0 + ty * TM + i;
#pragma unroll
        for (int j = 0; j < TN; ++j) {
            int nc = n0 + tx * TN + j;
            float x = acc[i][j];
            if (bias) x += bias[nc];
            outp[(size_t)mr * N + nc] = x;
        }
    }
}

// ======================= fused phase-shifted SNN step =======================
// grid = 128 row-tiles x 4 heads = 512 blocks, 256 threads, 8 rows per block.
// Phase A (t>0): LIF of step t-1 (weights read from ORIGINAL layouts, contiguous
// float4 per thread). Only hh==0 blocks write/count. Phase B: q/scores/softmax/PV
// of step t for this head, with double-buffered v staging.
__global__ __launch_bounds__(256) void fstep_k(
    const float* __restrict__ kT,          // [128][1024] k^T for this t
    const float* __restrict__ kv,          // [1024][256] (v half used)
    const float* __restrict__ A_w,         // [128][128]
    const float* __restrict__ Wq_w,        // [128][128]
    const float* __restrict__ bq_w,        // [128]
    const float* __restrict__ Wo_w,        // [128][128]
    const float* __restrict__ bo_w,        // [128]
    const float* __restrict__ C_w,         // [256][128]
    const float* __restrict__ h_old, float* __restrict__ h_new,
    const float* __restrict__ sv_in, float* __restrict__ sv_out,
    const float* __restrict__ ov_in, float* __restrict__ ov_out,
    const float* __restrict__ att_in, float* __restrict__ att_out,
    float* __restrict__ outs_prev,
    int* __restrict__ cnt1, int* __restrict__ cnt2, int t, int do_B)
{
    __shared__ float p_s[8][1032];         // row-major scores (row stride 16B-mult)
    __shared__ float v_s[2][64 * 36];      // double-buffered v chunk [key][36]
    __shared__ float hA_s[8 * 128];
    __shared__ float h2_s[8 * 128];
    __shared__ float att_s[8 * 128];
    __shared__ float q_s[8 * 36];
    __shared__ float red_s[8 * 33];
    __shared__ float mrow_s[8], linv_s[8], thr_s[2];

    const int tid = threadIdx.x;
    const int hh = blockIdx.x >> 7;
    const int r0 = (blockIdx.x & 127) * 8;
    const bool wrb = (hh == 0);

    if (t > 0) {
        if (tid == 0) {
            float ts = 1.0f, to = 1.0f;
            for (int i = 0; i < t - 1; ++i) {
                float e1 = (float)cnt1[i] * (1.f / 131072.f) - 0.02f;
                ts = fmaxf(ts + 0.1f * e1, 0.5f);
                float e2 = (float)cnt2[i] * (1.f / 262144.f) - 0.02f;
                to = fmaxf(to + 0.1f * e2, 0.5f);
            }
            thr_s[0] = ts; thr_s[1] = to;
        }
#pragma unroll
        for (int i = 0; i < 4; ++i) {
            int idx = i * 256 + tid;
            hA_s[idx]  = h_old[r0 * 128 + idx];
            att_s[idx] = att_in[r0 * 128 + idx];
        }
        __syncthreads();

        // ---- A1: st = h_old@A^T, b = att@Wo^T; upd -> LIF1 -> h2 ----
        {
            const int n = tid & 127, half = tid >> 7;
            const float* Ar  = A_w  + n * 128;
            const float* Wor = Wo_w + n * 128;
            float st[4] = {0.f, 0.f, 0.f, 0.f};
            float b[4]  = {0.f, 0.f, 0.f, 0.f};
            for (int k4 = 0; k4 < 32; ++k4) {
                const int k = k4 * 4;
                float4 wa = *(const float4*)(Ar + k);
                float4 wo = *(const float4*)(Wor + k);
#pragma unroll
                for (int r4 = 0; r4 < 4; ++r4) {
                    int r = half * 4 + r4;
                    float4 hv = *(const float4*)&hA_s[r * 128 + k];
                    float4 av = *(const float4*)&att_s[r * 128 + k];
                    st[r4] += hv.x * wa.x; st[r4] += hv.y * wa.y;
                    st[r4] += hv.z * wa.z; st[r4] += hv.w * wa.w;
                    b[r4] += av.x * wo.x; b[r4] += av.y * wo.y;
                    b[r4] += av.z * wo.z; b[r4] += av.w * wo.w;
                }
            }
            float ts = thr_s[0];
            int my1 = 0;
#pragma unroll
            for (int r4 = 0; r4 < 4; ++r4) {
                int r = half * 4 + r4, row = r0 + r;
                float x = b[r4] + bo_w[n];
                x += st[r4];
                float v = sv_in[row * 128 + n];
                float vp = v * DECAYF + x;
                float sp = (vp - ts >= 0.f) ? 1.f : 0.f;
                h2_s[r * 128 + n] = sp;
                if (wrb) {
                    h_new[row * 128 + n]  = sp;
                    sv_out[row * 128 + n] = vp * (1.f - sp);
                }
                my1 += (int)sp;
            }
            if (wrb) {
#pragma unroll
                for (int off = 32; off > 0; off >>= 1) my1 += __shfl_down(my1, off, 64);
                if ((tid & 63) == 0) atomicAdd(&cnt1[t - 1], my1);
            }
        }
        __syncthreads();

        // ---- A2: out_pot = h2@C^T -> LIF2 -> outs[t-1] (writer blocks only) ----
        if (wrb) {
            const int n = tid;
            const float* Cr = C_w + n * 128;
            float acc[8] = {0.f, 0.f, 0.f, 0.f, 0.f, 0.f, 0.f, 0.f};
            for (int k4 = 0; k4 < 32; ++k4) {
                const int k = k4 * 4;
                float4 wc = *(const float4*)(Cr + k);
#pragma unroll
                for (int r = 0; r < 8; ++r) {
                    float4 hv = *(const float4*)&h2_s[r * 128 + k];
                    acc[r] += hv.x * wc.x; acc[r] += hv.y * wc.y;
                    acc[r] += hv.z * wc.z; acc[r] += hv.w * wc.w;
                }
            }
            float to = thr_s[1];
            int my2 = 0;
#pragma unroll
            for (int r = 0; r < 8; ++r) {
                int row = r0 + r;
                float vo = ov_in[row * 256 + n];
                float vp = vo * DECAYF + acc[r];
                float sp = (vp - to >= 0.f) ? 1.f : 0.f;
                outs_prev[(size_t)row * 256 + n] = sp;
                ov_out[row * 256 + n] = vp * (1.f - sp);
                my2 += (int)sp;
            }
#pragma unroll
            for (int off = 32; off > 0; off >>= 1) my2 += __shfl_down(my2, off, 64);
            if ((tid & 63) == 0) atomicAdd(&cnt2[t - 1], my2);
        }
    } else {
#pragma unroll
        for (int i = 0; i < 4; ++i) {
            int idx = i * 256 + tid;
            h2_s[idx] = h_new[r0 * 128 + idx];   // zeros from init_k
        }
        __syncthreads();
    }

    if (!do_B) return;

    // ---- B1: q[r][d] for this head (ascending-k fma; Wq rows contiguous) ----
    {
        const int r = tid >> 5, d = tid & 31;
        const int j = hh * 32 + d;
        const float* Wqr = Wq_w + j * 128;
        float acc = 0.f;
        for (int k4 = 0; k4 < 32; ++k4) {
            const int k = k4 * 4;
            float4 wv = *(const float4*)(Wqr + k);
            float4 hv = *(const float4*)&h2_s[r * 128 + k];
            acc += hv.x * wv.x; acc += hv.y * wv.y;
            acc += hv.z * wv.z; acc += hv.w * wv.w;
        }
        q_s[r * 36 + d] = acc + bq_w[j];
    }
    __syncthreads();

    // ---- B2: scores. Wave w owns rows {2w,2w+1}; q in registers. ----
    {
        const int w = tid >> 6, lane = tid & 63;
        float4 qr0[8], qr1[8];
#pragma unroll
        for (int d4 = 0; d4 < 8; ++d4) {
            qr0[d4] = *(const float4*)&q_s[(2 * w) * 36 + d4 * 4];
            qr1[d4] = *(const float4*)&q_s[(2 * w + 1) * 36 + d4 * 4];
        }
        const float* kTh = kT + hh * 32 * 1024;
        for (int kk = 0; kk < 16; ++kk) {
            const int key = kk * 64 + lane;
            float kreg[32];
#pragma unroll
            for (int d = 0; d < 32; ++d) kreg[d] = kTh[d * 1024 + key];
            float a0 = 0.f, a1 = 0.f;
#pragma unroll
            for (int d4 = 0; d4 < 8; ++d4) {
                a0 += qr0[d4].x * kreg[d4 * 4 + 0]; a0 += qr0[d4].y * kreg[d4 * 4 + 1];
                a0 += qr0[d4].z * kreg[d4 * 4 + 2]; a0 += qr0[d4].w * kreg[d4 * 4 + 3];
                a1 += qr1[d4].x * kreg[d4 * 4 + 0]; a1 += qr1[d4].y * kreg[d4 * 4 + 1];
                a1 += qr1[d4].z * kreg[d4 * 4 + 2]; a1 += qr1[d4].w * kreg[d4 * 4 + 3];
            }
            p_s[2 * w][key]     = a0 * SCALEF;
            p_s[2 * w + 1][key] = a1 * SCALEF;
        }
    }
    __syncthreads();

    // ---- B3: softmax (identical per-row reduction order to rounds 1-4) ----
    {
        const int rh = tid >> 5, lg = tid & 31;
        float mx = -1e30f;
        for (int jj = 0; jj < 32; ++jj) mx = fmaxf(mx, p_s[rh][lg + 32 * jj]);
        red_s[rh * 33 + lg] = mx;
        __syncthreads();
        if (tid < 8) {
            float m = red_s[tid * 33];
            for (int j = 1; j < 32; ++j) m = fmaxf(m, red_s[tid * 33 + j]);
            mrow_s[tid] = m;
        }
        __syncthreads();
        float m = mrow_s[rh];
        float ls = 0.f;
        for (int jj = 0; jj < 32; ++jj) {
            int a = lg + 32 * jj;
            float p = expf(p_s[rh][a] - m);
            p_s[rh][a] = p;
            ls += p;
        }
        red_s[rh * 33 + lg] = ls;
        __syncthreads();
        if (tid < 8) {
            float l = 0.f;
            for (int j = 0; j < 32; ++j) l += red_s[tid * 33 + j];
            linv_s[tid] = 1.0f / l;
        }
    }
    __syncthreads();

    // ---- B4: PV, double-buffered v staging; thread tile 2 rows x 2 dims. ----
    {
        const int rp = (tid >> 4) & 3;     // row-pair (rows 2rp, 2rp+1)
        const int dp = tid & 15;           // dim-pair (dims 2dp, 2dp+1)
        const float4* kv4 = (const float4*)kv;
        float4 stg0, stg1;
        {
            int i0 = tid, i1 = 256 + tid;
            stg0 = kv4[(size_t)(i0 >> 3) * 64 + 32 + hh * 8 + (i0 & 7)];
            stg1 = kv4[(size_t)(i1 >> 3) * 64 + 32 + hh * 8 + (i1 & 7)];
        }
        float a00 = 0.f, a01 = 0.f, a10 = 0.f, a11 = 0.f;
        for (int c = 0; c < 16; ++c) {
            float* vb = &v_s[c & 1][0];
            {
                int i0 = tid, i1 = 256 + tid;
                *(float4*)&vb[(i0 >> 3) * 36 + (i0 & 7) * 4] = stg0;
                *(float4*)&vb[(i1 >> 3) * 36 + (i1 & 7) * 4] = stg1;
            }
            if (c < 15) {
                int i0 = tid, i1 = 256 + tid;
                stg0 = kv4[(size_t)((c + 1) * 64 + (i0 >> 3)) * 64 + 32 + hh * 8 + (i0 & 7)];
                stg1 = kv4[(size_t)((c + 1) * 64 + (i1 >> 3)) * 64 + 32 + hh * 8 + (i1 & 7)];
            }
            __syncthreads();
            if (tid < 64) {
#pragma unroll 4
                for (int k4 = 0; k4 < 16; ++k4) {
                    const int kb = k4 * 4;
                    float4 p0 = *(const float4*)&p_s[2 * rp][c * 64 + kb];
                    float4 p1 = *(const float4*)&p_s[2 * rp + 1][c * 64 + kb];
                    float2 v0 = *(const float2*)&vb[(kb + 0) * 36 + 2 * dp];
                    float2 v1 = *(const float2*)&vb[(kb + 1) * 36 + 2 * dp];
                    float2 v2 = *(const float2*)&vb[(kb + 2) * 36 + 2 * dp];
                    float2 v3 = *(const float2*)&vb[(kb + 3) * 36 + 2 * dp];
                    a00 += p0.x * v0.x; a01 += p0.x * v0.y;
                    a10 += p1.x * v0.x; a11 += p1.x * v0.y;
                    a00 += p0.y * v1.x; a01 += p0.y * v1.y;
                    a10 += p1.y * v1.x; a11 += p1.y * v1.y;
                    a00 += p0.z * v2.x; a01 += p0.z * v2.y;
                    a10 += p1.z * v2.x; a11 += p1.z * v2.y;
                    a00 += p0.w * v3.x; a01 += p0.w * v3.y;
                    a10 += p1.w * v3.x; a11 += p1.w * v3.y;
                }
            }
        }
        if (tid < 64) {
            float li0 = linv_s[2 * rp], li1 = linv_s[2 * rp + 1];
            *(float2*)&att_out[(size_t)(r0 + 2 * rp) * 128 + hh * 32 + 2 * dp] =
                make_float2(a00 * li0, a01 * li0);
            *(float2*)&att_out[(size_t)(r0 + 2 * rp + 1) * 128 + hh * 32 + 2 * dp] =
                make_float2(a10 * li1, a11 * li1);
        }
    }
}

// ======================= host =======================
extern "C" void kernel_launch(void* const* d_in, const int* in_sizes, int n_in,
                              void* d_out, int out_size, void* d_ws, size_t ws_size,
                              hipStream_t stream) {
    (void)in_sizes; (void)n_in; (void)out_size; (void)ws_size;
    const int*   ids  = (const int*)d_in[0];
    const float* emb  = (const float*)d_in[1];
    const float* Aw   = (const float*)d_in[2];
    const float* Cw   = (const float*)d_in[3];
    const float* Wq   = (const float*)d_in[4];
    const float* bq   = (const float*)d_in[5];
    const float* Wkv  = (const float*)d_in[6];
    const float* bkv  = (const float*)d_in[7];
    const float* Wo   = (const float*)d_in[8];
    const float* bo   = (const float*)d_in[9];
    const float* Wout = (const float*)d_in[10];
    const float* bout = (const float*)d_in[11];
    float* out = (float*)d_out;
    float* ws  = (float*)d_ws;

    float* tok  = ws;                       // 262144
    float* bufA = tok  + NE;                // 8*262144
    float* bufB = bufA + 8 * NE;            // 8*262144
    float* kvb  = bufB + 8 * NE;            // 8*262144
    float* kTb  = kvb  + 8 * NE;            // 8*131072
    float* attb0 = kTb  + 8 * 131072;       // 131072
    float* attb1 = attb0 + 131072;          // 131072
    float* hb0  = attb1 + 131072;           // 131072
    float* hb1  = hb0  + 131072;            // 131072
    float* svb0 = hb1  + 131072;            // 131072
    float* svb1 = svb0 + 131072;            // 131072
    float* ovb0 = svb1 + 131072;            // 262144
    float* ovb1 = ovb0 + 262144;            // 262144
    float* ti   = ovb1 + 262144;            // 262144
    int*   cnts = (int*)(ti + NE);          // cnt1[8], cnt2[8]

    float* hb[2]   = {hb0, hb1};
    float* svb[2]  = {svb0, svb1};
    float* ovb[2]  = {ovb0, ovb1};
    float* attb[2] = {attb0, attb1};

    embed_k<<<dim3(1024), dim3(256), 0, stream>>>(ids, emb, tok);

    for (int l = 0; l < 2; ++l) {
        const float* Al   = Aw  + l * 16384;
        const float* Cl   = Cw  + l * 32768;
        const float* Wql  = Wq  + l * 16384;
        const float* bql  = bq  + l * 128;
        const float* Wkvl = Wkv + l * 65536;
        const float* bkvl = bkv + l * 256;
        const float* Wol  = Wo  + l * 16384;
        const float* bol  = bo  + l * 128;
        const float* xin  = (l == 0) ? tok : bufA;
        float* outs       = (l == 0) ? bufA : bufB;
        const int Mkv     = (l == 0) ? BS_TOT : 8 * BS_TOT;
        const int nt      = (l == 0) ? 1 : 8;

        init_k<<<dim3(1024), dim3(256), 0, stream>>>(hb0, hb1, svb0, svb1,
                                                     ovb0, ovb1, cnts);

        gemm_k<64, 64, 16, 4, 4><<<dim3(256 / 64, Mkv / 64), dim3(256), 0, stream>>>(
            xin, Wkvl, bkvl, kvb, Mkv, 256, 256);

        ktrans_k<<<dim3(16, nt), dim3(256), 0, stream>>>(kvb, kTb);

        for (int t = 0; t <= TSTEPS; ++t) {
            const int do_B = (t < TSTEPS) ? 1 : 0;
            const int tt = (t < TSTEPS) ? t : (TSTEPS - 1);
            const float* kT_t = (l == 0) ? kTb : kTb + (size_t)tt * 131072;
            const float* kv_t = (l == 0) ? kvb : kvb + (size_t)tt * NE;
            float* outs_prev = outs + (size_t)((t > 0) ? (t - 1) : 0) * NE;
            const int grid = do_B ? 512 : 128;
            fstep_k<<<dim3(grid), dim3(256), 0, stream>>>(
                kT_t, kv_t, Al, Wql, bql, Wol, bol, Cl,
                hb[t & 1], hb[(t + 1) & 1],
                svb[t & 1], svb[(t + 1) & 1],
                ovb[t & 1], ovb[(t + 1) & 1],
                attb[(t + 1) & 1], attb[t & 1],
                outs_prev, cnts, cnts + 8, t, do_B);
        }
    }

    mean_k<<<dim3(1024), dim3(256), 0, stream>>>(bufB, ti);

    // logits = ti @ Wout^T + bout (round-1 measured config: ~216 us)
    gemm_k<64, 64, 16, 4, 4><<<dim3(32000 / 64, BS_TOT / 64), dim3(256), 0, stream>>>(
        ti, Wout, bout, out, BS_TOT, 32000, 256);
}

// Round 6
// 1246.725 us; speedup vs baseline: 1.0834x; 1.0834x over previous
//
#include <hip/hip_runtime.h>
#include <math.h>

// ---- model constants ----
#define BS_TOT   1024          // B*S
#define DM       256           // d_model
#define DST      128           // d_state
#define TSTEPS   8
#define DECAYF   0.6065306597126334f
#define SCALEF   0.17677669529663689f   // 1/sqrt(32)
#define NE       (BS_TOT * DM)          // 262144

// ======================= embedding =======================
__global__ void embed_k(const int* __restrict__ ids, const float* __restrict__ emb,
                        float* __restrict__ tok) {
    int r = blockIdx.x, c = threadIdx.x;
    tok[r * DM + c] = emb[(size_t)ids[r] * DM + c];
}

// ======================= per-layer prep: zero state + transpose weights ==========
// grid 1024 x 256 (262144 threads)
__global__ void prep_k(float* __restrict__ h, float* __restrict__ sv, float* __restrict__ ov,
                       float* __restrict__ W1T, float* __restrict__ WoT, float* __restrict__ CT,
                       const float* __restrict__ Al, const float* __restrict__ Wql,
                       const float* __restrict__ Wol, const float* __restrict__ Cl,
                       int* __restrict__ cnts) {
    int i = blockIdx.x * 256 + threadIdx.x;
    if (i < BS_TOT * DST) { h[i] = 0.f; sv[i] = 0.f; }
    ov[i] = 0.f;
    if (i < 32768) {
        int k = i >> 8, n = i & 255;
        W1T[i] = (n < 128) ? Al[n * 128 + k] : Wql[(n - 128) * 128 + k];
        CT[i]  = Cl[n * 128 + k];
    }
    if (i < 16384) {
        int k = i >> 7, n = i & 127;
        WoT[i] = Wol[n * 128 + k];
    }
    if (i < 16) cnts[i] = 0;
}

// ======================= k-half transpose: kv[key][0..127] -> kT[d][key] =========
__global__ __launch_bounds__(256) void ktrans_k(const float* __restrict__ kv,
                                                float* __restrict__ kT) {
    __shared__ float tile[64][133];
    const float* src = kv + (size_t)blockIdx.y * NE;
    float* dst = kT + (size_t)blockIdx.y * (128 * 1024);
    const int kc = blockIdx.x, tid = threadIdx.x;
#pragma unroll
    for (int i = 0; i < 32; ++i) {
        int idx = i * 256 + tid;
        int key = idx >> 7, d = idx & 127;
        tile[key][d] = src[(size_t)(kc * 64 + key) * 256 + d];
    }
    __syncthreads();
#pragma unroll
    for (int i = 0; i < 32; ++i) {
        int idx = i * 256 + tid;
        int d = idx >> 6, key = idx & 63;
        dst[(size_t)d * 1024 + kc * 64 + key] = tile[key][d];
    }
}

// ======================= time-mean =======================
__global__ void mean_k(const float* __restrict__ outs, float* __restrict__ ti) {
    int i = blockIdx.x * 256 + threadIdx.x;
    float s = 0.f;
#pragma unroll
    for (int t = 0; t < TSTEPS; ++t) s += outs[t * NE + i];
    ti[i] = s * 0.125f;
}

// ======================= generic fp32 GEMM (plain, +bias) =======================
template <int BM, int BN, int BK, int TM, int TN>
__global__ __launch_bounds__((BM / TM) * (BN / TN))
void gemm_k(const float* __restrict__ Amat, const float* __restrict__ Wmat,
            const float* __restrict__ bias, float* __restrict__ outp,
            int M, int N, int K) {
    constexpr int NT  = (BM / TM) * (BN / TN);
    constexpr int NXT = BN / TN;
    __shared__ float As[BK][BM + 4];
    __shared__ float Bs[BK][BN + 4];
    const int tid = threadIdx.x;
    const int n0 = blockIdx.x * BN, m0 = blockIdx.y * BM;
    const int tx = tid % NXT, ty = tid / NXT;
    float acc[TM][TN] = {};

    for (int k0 = 0; k0 < K; k0 += BK) {
#pragma unroll
        for (int i = 0; i < (BM * BK) / NT; ++i) {
            int idx = i * NT + tid;
            int kk = idx % BK, mm = idx / BK;
            As[kk][mm] = Amat[(size_t)(m0 + mm) * K + k0 + kk];
        }
#pragma unroll
        for (int i = 0; i < (BN * BK) / NT; ++i) {
            int idx = i * NT + tid;
            int kk = idx % BK, nn = idx / BK;
            Bs[kk][nn] = Wmat[(size_t)(n0 + nn) * K + k0 + kk];
        }
        __syncthreads();
#pragma unroll
        for (int kk = 0; kk < BK; ++kk) {
            float a[TM], b[TN];
#pragma unroll
            for (int i = 0; i < TM; ++i) a[i] = As[kk][ty * TM + i];
#pragma unroll
            for (int j = 0; j < TN; ++j) b[j] = Bs[kk][tx * TN + j];
#pragma unroll
            for (int i = 0; i < TM; ++i)
#pragma unroll
                for (int j = 0; j < TN; ++j) acc[i][j] += a[i] * b[j];
        }
        __syncthreads();
    }
#pragma unroll
    for (int i = 0; i < TM; ++i) {
        int mr = m0 + ty * TM + i;
#pragma unroll
        for (int j = 0; j < TN; ++j) {
            int nc = n0 + tx * TN + j;
            float x = acc[i][j];
            if (bias) x += bias[nc];
            outp[(size_t)mr * N + nc] = x;
        }
    }
}

// ======================= L-kernel: LIF of step t-1 + q of step t ==================
// grid 256 blocks x 256 thr, 4 rows per block. Sparse (spike-mask) matmuls with
// coalesced transposed-weight reads; all summation chains ascending-k bit-exact.
__global__ __launch_bounds__(256) void lif_k(
    const float* __restrict__ W1T,        // [128][256]  ([A|Wq] transposed)
    const float* __restrict__ WoT,        // [128][128]
    const float* __restrict__ CT,         // [128][256]
    const float* __restrict__ bq_w,       // [128]
    const float* __restrict__ bo_w,       // [128]
    float* __restrict__ h,                // [1024][128] spikes (in/out, in-place)
    float* __restrict__ sv,               // [1024][128]
    float* __restrict__ ov,               // [1024][256]
    const float* __restrict__ att_in,     // [1024][128]  att(t-1)
    float* __restrict__ outs_prev,        // outs[t-1]
    float* __restrict__ q_g,              // [1024][128]
    int* __restrict__ cnt1, int* __restrict__ cnt2, int t, int do_B)
{
    __shared__ float hA_s[4 * 128];
    __shared__ float h2_s[4 * 128];
    __shared__ float att_s[4 * 128];
    __shared__ unsigned long long umr_s[4][2];
    __shared__ unsigned long long um_s[2];
    __shared__ float thr_s[2];

    const int tid = threadIdx.x;
    const int r0 = blockIdx.x * 4;

    if (tid == 0) {
        float ts = 1.0f, to = 1.0f;
        for (int i = 0; i < t - 1; ++i) {
            float e1 = (float)cnt1[i] * (1.f / 131072.f) - 0.02f;
            ts = fmaxf(ts + 0.1f * e1, 0.5f);
            float e2 = (float)cnt2[i] * (1.f / 262144.f) - 0.02f;
            to = fmaxf(to + 0.1f * e2, 0.5f);
        }
        thr_s[0] = ts; thr_s[1] = to;
    }
    hA_s[tid]       = h[r0 * 128 + tid];
    hA_s[256 + tid] = h[r0 * 128 + 256 + tid];
    if (t > 0) {
        att_s[tid]       = att_in[r0 * 128 + tid];
        att_s[256 + tid] = att_in[r0 * 128 + 256 + tid];
    }
    __syncthreads();
    {   // per-row ballots of h_old (wave w -> row w)
        int w = tid >> 6, l = tid & 63;
        unsigned long long b0 = __ballot(hA_s[w * 128 + l] != 0.f);
        unsigned long long b1 = __ballot(hA_s[w * 128 + 64 + l] != 0.f);
        if (l == 0) { umr_s[w][0] = b0; umr_s[w][1] = b1; }
    }
    __syncthreads();
    if (tid == 0) {
        um_s[0] = umr_s[0][0] | umr_s[1][0] | umr_s[2][0] | umr_s[3][0];
        um_s[1] = umr_s[0][1] | umr_s[1][1] | umr_s[2][1] | umr_s[3][1];
    }
    __syncthreads();

    const int n = tid & 127, half = tid >> 7;   // rows 2*half, 2*half+1
    const int ra = half * 2, rb = half * 2 + 1;

    if (t > 0) {
        // ---- A1: st = h_old@A^T (sparse), b = att@Wo^T (dense); LIF1 -> h2 ----
        float sta = 0.f, stb = 0.f;
        unsigned long long u = um_s[0];
        while (u) {
            int k = __builtin_ctzll(u); u &= u - 1;
            float w = W1T[(k << 8) + n];
            sta += hA_s[ra * 128 + k] * w; stb += hA_s[rb * 128 + k] * w;
        }
        u = um_s[1];
        while (u) {
            int kk = __builtin_ctzll(u); u &= u - 1;
            int k = 64 + kk;
            float w = W1T[(k << 8) + n];
            sta += hA_s[ra * 128 + k] * w; stb += hA_s[rb * 128 + k] * w;
        }
        float ba = 0.f, bb = 0.f;
        for (int i4 = 0; i4 < 32; ++i4) {
            const int i = i4 * 4;
            float w0 = WoT[(i + 0) * 128 + n];
            float w1 = WoT[(i + 1) * 128 + n];
            float w2 = WoT[(i + 2) * 128 + n];
            float w3 = WoT[(i + 3) * 128 + n];
            float4 aa = *(const float4*)&att_s[ra * 128 + i];
            float4 ab = *(const float4*)&att_s[rb * 128 + i];
            ba += aa.x * w0; ba += aa.y * w1; ba += aa.z * w2; ba += aa.w * w3;
            bb += ab.x * w0; bb += ab.y * w1; bb += ab.z * w2; bb += ab.w * w3;
        }
        float ts = thr_s[0];
        float xa = ba + bo_w[n]; xa += sta;
        float va = sv[(r0 + ra) * 128 + n];
        float vpa = va * DECAYF + xa;
        float spa = (vpa - ts >= 0.f) ? 1.f : 0.f;
        h[(r0 + ra) * 128 + n]  = spa;
        sv[(r0 + ra) * 128 + n] = vpa * (1.f - spa);
        h2_s[ra * 128 + n] = spa;

        float xb = bb + bo_w[n]; xb += stb;
        float vb = sv[(r0 + rb) * 128 + n];
        float vpb = vb * DECAYF + xb;
        float spb = (vpb - ts >= 0.f) ? 1.f : 0.f;
        h[(r0 + rb) * 128 + n]  = spb;
        sv[(r0 + rb) * 128 + n] = vpb * (1.f - spb);
        h2_s[rb * 128 + n] = spb;

        unsigned long long bba = __ballot(spa != 0.f);
        unsigned long long bbb = __ballot(spb != 0.f);
        int w = tid >> 6, l = tid & 63;
        if (l == 0) {
            umr_s[ra][w & 1] = bba;
            umr_s[rb][w & 1] = bbb;
            atomicAdd(&cnt1[t - 1], __popcll(bba) + __popcll(bbb));
        }
    } else {
        h2_s[tid]       = hA_s[tid];          // zeros
        h2_s[256 + tid] = hA_s[256 + tid];
        // umr stays = zero ballots of h
    }
    __syncthreads();
    if (tid == 0) {
        um_s[0] = umr_s[0][0] | umr_s[1][0] | umr_s[2][0] | umr_s[3][0];
        um_s[1] = umr_s[0][1] | umr_s[1][1] | umr_s[2][1] | umr_s[3][1];
    }
    __syncthreads();

    if (t > 0) {
        // ---- A2: out_pot = h2@C^T (sparse) -> LIF2 -> outs[t-1] ----
        const int n2 = tid;
        float a0 = 0.f, a1 = 0.f, a2 = 0.f, a3 = 0.f;
        unsigned long long u = um_s[0];
        while (u) {
            int k = __builtin_ctzll(u); u &= u - 1;
            float w = CT[(k << 8) + n2];
            a0 += h2_s[k] * w;       a1 += h2_s[128 + k] * w;
            a2 += h2_s[256 + k] * w; a3 += h2_s[384 + k] * w;
        }
        u = um_s[1];
        while (u) {
            int kk = __builtin_ctzll(u); u &= u - 1;
            int k = 64 + kk;
            float w = CT[(k << 8) + n2];
            a0 += h2_s[k] * w;       a1 += h2_s[128 + k] * w;
            a2 += h2_s[256 + k] * w; a3 += h2_s[384 + k] * w;
        }
        float to = thr_s[1];
        float accs[4] = {a0, a1, a2, a3};
        float sp[4];
#pragma unroll
        for (int r = 0; r < 4; ++r) {
            float vo = ov[(r0 + r) * 256 + n2];
            float vp = vo * DECAYF + accs[r];
            float s = (vp - to >= 0.f) ? 1.f : 0.f;
            sp[r] = s;
            outs_prev[(size_t)(r0 + r) * 256 + n2] = s;
            ov[(r0 + r) * 256 + n2] = vp * (1.f - s);
        }
        unsigned long long c0 = __ballot(sp[0] != 0.f);
        unsigned long long c1 = __ballot(sp[1] != 0.f);
        unsigned long long c2 = __ballot(sp[2] != 0.f);
        unsigned long long c3 = __ballot(sp[3] != 0.f);
        if ((tid & 63) == 0)
            atomicAdd(&cnt2[t - 1], __popcll(c0) + __popcll(c1) + __popcll(c2) + __popcll(c3));
    }

    if (do_B) {
        // ---- B1: q = h2@Wq^T + bq (sparse), cols 128..255 of W1T ----
        float qa = 0.f, qb = 0.f;
        unsigned long long u = um_s[0];
        while (u) {
            int k = __builtin_ctzll(u); u &= u - 1;
            float w = W1T[(k << 8) + 128 + n];
            qa += h2_s[ra * 128 + k] * w; qb += h2_s[rb * 128 + k] * w;
        }
        u = um_s[1];
        while (u) {
            int kk = __builtin_ctzll(u); u &= u - 1;
            int k = 64 + kk;
            float w = W1T[(k << 8) + 128 + n];
            qa += h2_s[ra * 128 + k] * w; qb += h2_s[rb * 128 + k] * w;
        }
        q_g[(r0 + ra) * 128 + n] = qa + bq_w[n];
        q_g[(r0 + rb) * 128 + n] = qb + bq_w[n];
    }
}

// ======================= S-kernel: scores/softmax/PV for one head =================
// grid = 128 row-tiles x 4 heads = 512 blocks, 256 threads, 8 rows per block.
__global__ __launch_bounds__(256) void attn_k(
    const float* __restrict__ q_g,        // [1024][128]
    const float* __restrict__ kT,         // [128][1024]
    const float* __restrict__ kv,         // [1024][256] (v half used)
    float* __restrict__ att_out)          // [1024][128]
{
    __shared__ float p_s[8][1032];
    __shared__ float v_s[64 * 36];
    __shared__ float q_s[8][32];
    __shared__ float red_s[8 * 33];
    __shared__ float mrow_s[8], linv_s[8];

    const int tid = threadIdx.x;
    const int hh = blockIdx.x >> 7;
    const int r0 = (blockIdx.x & 127) * 8;

    {   // stage q (8 rows x 32 dims)
        int r = tid >> 5, d = tid & 31;
        q_s[r][d] = q_g[(size_t)(r0 + r) * 128 + hh * 32 + d];
    }
    __syncthreads();

    // ---- B2: scores. Lane owns 4 keys; 2 d-passes continue one ascending chain.
    {
        const int w = tid >> 6, l = tid & 63;
        const int key4 = w * 64 + l;                 // float4 index into 1024 keys
        const float4* kT4 = (const float4*)(kT + (size_t)hh * 32 * 1024);
        float4 acc[8];
#pragma unroll
        for (int pass = 0; pass < 2; ++pass) {
            const int d0 = pass * 16;
            float4 kreg[16];
#pragma unroll
            for (int i = 0; i < 16; ++i) kreg[i] = kT4[(size_t)(d0 + i) * 256 + key4];
#pragma unroll
            for (int r = 0; r < 8; ++r)
                acc[r] = pass ? *(const float4*)&p_s[r][key4 * 4]
                              : make_float4(0.f, 0.f, 0.f, 0.f);
#pragma unroll
            for (int i4 = 0; i4 < 4; ++i4) {
#pragma unroll
                for (int r = 0; r < 8; ++r) {
                    float4 qv = *(const float4*)&q_s[r][d0 + i4 * 4];
                    float4 k0 = kreg[i4 * 4 + 0], k1 = kreg[i4 * 4 + 1];
                    float4 k2 = kreg[i4 * 4 + 2], k3 = kreg[i4 * 4 + 3];
                    acc[r].x += qv.x * k0.x; acc[r].x += qv.y * k1.x;
                    acc[r].x += qv.z * k2.x; acc[r].x += qv.w * k3.x;
                    acc[r].y += qv.x * k0.y; acc[r].y += qv.y * k1.y;
                    acc[r].y += qv.z * k2.y; acc[r].y += qv.w * k3.y;
                    acc[r].z += qv.x * k0.z; acc[r].z += qv.y * k1.z;
                    acc[r].z += qv.z * k2.z; acc[r].z += qv.w * k3.z;
                    acc[r].w += qv.x * k0.w; acc[r].w += qv.y * k1.w;
                    acc[r].w += qv.z * k2.w; acc[r].w += qv.w * k3.w;
                }
            }
            if (pass == 0) {
#pragma unroll
                for (int r = 0; r < 8; ++r)
                    *(float4*)&p_s[r][key4 * 4] = acc[r];
            } else {
#pragma unroll
                for (int r = 0; r < 8; ++r) {
                    acc[r].x *= SCALEF; acc[r].y *= SCALEF;
                    acc[r].z *= SCALEF; acc[r].w *= SCALEF;
                    *(float4*)&p_s[r][key4 * 4] = acc[r];
                }
            }
        }
    }
    __syncthreads();

    // ---- B3: softmax (identical per-row reduction order to rounds 1-5) ----
    {
        const int rh = tid >> 5, lg = tid & 31;
        float mx = -1e30f;
        for (int jj = 0; jj < 32; ++jj) mx = fmaxf(mx, p_s[rh][lg + 32 * jj]);
        red_s[rh * 33 + lg] = mx;
        __syncthreads();
        if (tid < 8) {
            float m = red_s[tid * 33];
            for (int j = 1; j < 32; ++j) m = fmaxf(m, red_s[tid * 33 + j]);
            mrow_s[tid] = m;
        }
        __syncthreads();
        float m = mrow_s[rh];
        float ls = 0.f;
        for (int jj = 0; jj < 32; ++jj) {
            int a = lg + 32 * jj;
            float p = expf(p_s[rh][a] - m);
            p_s[rh][a] = p;
            ls += p;
        }
        red_s[rh * 33 + lg] = ls;
        __syncthreads();
        if (tid < 8) {
            float l = 0.f;
            for (int j = 0; j < 32; ++j) l += red_s[tid * 33 + j];
            linv_s[tid] = 1.0f / l;
        }
    }
    __syncthreads();

    // ---- B4: PV. Waves 0,1 compute (4 rows x 16 dim-pairs each); all stage. ----
    {
        const int w = tid >> 6, l = tid & 63;
        const int r = (w & 1) * 4 + (l >> 4);
        const int dp = l & 15;
        const bool act = (w < 2);
        const float4* kv4 = (const float4*)kv;
        float4 stg0, stg1;
        {
            int i0 = tid, i1 = 256 + tid;
            stg0 = kv4[(size_t)(i0 >> 3) * 64 + 32 + hh * 8 + (i0 & 7)];
            stg1 = kv4[(size_t)(i1 >> 3) * 64 + 32 + hh * 8 + (i1 & 7)];
        }
        float a0 = 0.f, a1 = 0.f;
        for (int c = 0; c < 16; ++c) {
            {
                int i0 = tid, i1 = 256 + tid;
                *(float4*)&v_s[(i0 >> 3) * 36 + (i0 & 7) * 4] = stg0;
                *(float4*)&v_s[(i1 >> 3) * 36 + (i1 & 7) * 4] = stg1;
            }
            if (c < 15) {
                int i0 = tid, i1 = 256 + tid;
                stg0 = kv4[(size_t)((c + 1) * 64 + (i0 >> 3)) * 64 + 32 + hh * 8 + (i0 & 7)];
                stg1 = kv4[(size_t)((c + 1) * 64 + (i1 >> 3)) * 64 + 32 + hh * 8 + (i1 & 7)];
            }
            __syncthreads();
            if (act) {
#pragma unroll 4
                for (int k4 = 0; k4 < 16; ++k4) {
                    const int kb = k4 * 4;
                    float4 p4 = *(const float4*)&p_s[r][c * 64 + kb];
                    float2 v0 = *(const float2*)&v_s[(kb + 0) * 36 + 2 * dp];
                    float2 v1 = *(const float2*)&v_s[(kb + 1) * 36 + 2 * dp];
                    float2 v2 = *(const float2*)&v_s[(kb + 2) * 36 + 2 * dp];
                    float2 v3 = *(const float2*)&v_s[(kb + 3) * 36 + 2 * dp];
                    a0 += p4.x * v0.x; a1 += p4.x * v0.y;
                    a0 += p4.y * v1.x; a1 += p4.y * v1.y;
                    a0 += p4.z * v2.x; a1 += p4.z * v2.y;
                    a0 += p4.w * v3.x; a1 += p4.w * v3.y;
                }
            }
            __syncthreads();
        }
        if (act) {
            float li = linv_s[r];
            *(float2*)&att_out[(size_t)(r0 + r) * 128 + hh * 32 + 2 * dp] =
                make_float2(a0 * li, a1 * li);
        }
    }
}

// ======================= host =======================
extern "C" void kernel_launch(void* const* d_in, const int* in_sizes, int n_in,
                              void* d_out, int out_size, void* d_ws, size_t ws_size,
                              hipStream_t stream) {
    (void)in_sizes; (void)n_in; (void)out_size; (void)ws_size;
    const int*   ids  = (const int*)d_in[0];
    const float* emb  = (const float*)d_in[1];
    const float* Aw   = (const float*)d_in[2];
    const float* Cw   = (const float*)d_in[3];
    const float* Wq   = (const float*)d_in[4];
    const float* bq   = (const float*)d_in[5];
    const float* Wkv  = (const float*)d_in[6];
    const float* bkv  = (const float*)d_in[7];
    const float* Wo   = (const float*)d_in[8];
    const float* bo   = (const float*)d_in[9];
    const float* Wout = (const float*)d_in[10];
    const float* bout = (const float*)d_in[11];
    float* out = (float*)d_out;
    float* ws  = (float*)d_ws;

    float* tok  = ws;                       // 262144
    float* bufA = tok  + NE;                // 8*262144
    float* bufB = bufA + 8 * NE;            // 8*262144
    float* kvb  = bufB + 8 * NE;            // 8*262144
    float* kTb  = kvb  + 8 * NE;            // 8*131072
    float* attb = kTb  + 8 * 131072;        // 131072
    float* hbuf = attb + 131072;            // 131072
    float* svb  = hbuf + 131072;            // 131072
    float* ovb  = svb  + 131072;            // 262144
    float* qg   = ovb  + 262144;            // 131072
    float* ti   = qg   + 131072;            // 262144
    float* W1T  = ti   + NE;                // 32768
    float* WoT  = W1T  + 32768;             // 16384
    float* CT   = WoT  + 16384;             // 32768
    int*   cnts = (int*)(CT + 32768);       // cnt1[8], cnt2[8]

    embed_k<<<dim3(1024), dim3(256), 0, stream>>>(ids, emb, tok);

    for (int l = 0; l < 2; ++l) {
        const float* Al   = Aw  + l * 16384;
        const float* Cl   = Cw  + l * 32768;
        const float* Wql  = Wq  + l * 16384;
        const float* bql  = bq  + l * 128;
        const float* Wkvl = Wkv + l * 65536;
        const float* bkvl = bkv + l * 256;
        const float* Wol  = Wo  + l * 16384;
        const float* bol  = bo  + l * 128;
        const float* xin  = (l == 0) ? tok : bufA;
        float* outs       = (l == 0) ? bufA : bufB;
        const int Mkv     = (l == 0) ? BS_TOT : 8 * BS_TOT;
        const int nt      = (l == 0) ? 1 : 8;

        prep_k<<<dim3(1024), dim3(256), 0, stream>>>(hbuf, svb, ovb, W1T, WoT, CT,
                                                     Al, Wql, Wol, Cl, cnts);

        gemm_k<64, 64, 16, 4, 4><<<dim3(256 / 64, Mkv / 64), dim3(256), 0, stream>>>(
            xin, Wkvl, bkvl, kvb, Mkv, 256, 256);

        ktrans_k<<<dim3(16, nt), dim3(256), 0, stream>>>(kvb, kTb);

        for (int t = 0; t <= TSTEPS; ++t) {
            const int do_B = (t < TSTEPS) ? 1 : 0;
            float* outs_prev = outs + (size_t)((t > 0) ? (t - 1) : 0) * NE;
            lif_k<<<dim3(256), dim3(256), 0, stream>>>(
                W1T, WoT, CT, bql, bol,
                hbuf, svb, ovb, attb, outs_prev, qg,
                cnts, cnts + 8, t, do_B);
            if (do_B) {
                const float* kT_t = (l == 0) ? kTb : kTb + (size_t)t * 131072;
                const float* kv_t = (l == 0) ? kvb : kvb + (size_t)t * NE;
                attn_k<<<dim3(512), dim3(256), 0, stream>>>(qg, kT_t, kv_t, attb);
            }
        }
    }

    mean_k<<<dim3(1024), dim3(256), 0, stream>>>(bufB, ti);

    // logits = ti @ Wout^T + bout (measured-best config: ~214 us)
    gemm_k<64, 64, 16, 4, 4><<<dim3(32000 / 64, BS_TOT / 64), dim3(256), 0, stream>>>(
        ti, Wout, bout, out, BS_TOT, 32000, 256);
}